// Round 9
// baseline (648.522 us; speedup 1.0000x reference)
//
#include <hip/hip_runtime.h>
#include <hip/hip_cooperative_groups.h>

namespace cg = cooperative_groups;

typedef unsigned short u16;
typedef short short8 __attribute__((ext_vector_type(8)));
typedef float f32x4 __attribute__((ext_vector_type(4)));
typedef float float4v __attribute__((ext_vector_type(4)));
typedef u16 u16x4 __attribute__((ext_vector_type(4)));
typedef unsigned uint2v __attribute__((ext_vector_type(2)));
typedef unsigned long long u64;

// ---------- helpers ----------
__device__ __forceinline__ u16 f2bf(float f) {
  union { float f; unsigned u; } v; v.f = f;
  unsigned r = v.u + 0x7FFFu + ((v.u >> 16) & 1u);   // round-to-nearest-even
  return (u16)(r >> 16);
}

__device__ __forceinline__ unsigned cvtpk(float lo, float hi) {
  unsigned r;
  asm("v_cvt_pk_bf16_f32 %0, %1, %2" : "=v"(r) : "v"(lo), "v"(hi));
  return r;
}

__device__ __forceinline__ void gload16(const u16* g, u16* l) {
  __builtin_amdgcn_global_load_lds(
      (const __attribute__((address_space(1))) void*)g,
      (__attribute__((address_space(3))) void*)l, 16, 0, 0);
}

union PackSS { unsigned u[4]; short8 s; };

// ================= phase: prep (maskbits + xcvt + wcvt), block-strided =======
__device__ void phase_prep(char* sm, const void* mask, u64* __restrict__ bits,
                           const float* __restrict__ x, u16* __restrict__ xb,
                           const float* __restrict__ W0, const float* __restrict__ W1,
                           const float* __restrict__ W2, const float* __restrict__ W3,
                           u16* __restrict__ Wt, int bid, int nb) {
  __shared__ int sf;
  if (threadIdx.x == 0) sf = 0;
  __syncthreads();
  {  // detect mask dtype once per block from first 4KB (fmt: 0=u8,1=i32,2=f32,3=i64)
    uint4 v = ((const uint4*)mask)[threadIdx.x];
    unsigned xs[4] = {v.x, v.y, v.z, v.w};
    int f = 0;
#pragma unroll
    for (int d = 0; d < 4; ++d) {
      unsigned u = xs[d];
      if (u == 0x3F800000u) f |= 1;
      if (u & 0xFFFFFF00u) f |= 2;
      if ((d & 1) && u) f |= 4;
    }
    if (f) atomicOr(&sf, f);
  }
  __syncthreads();
  const int fl = sf;
  const int fmt = (fl & 1) ? 2 : ((fl & 2) ? 0 : ((fl & 4) ? 1 : 3));
  float (*t)[33] = (float (*)[33])sm;

  for (int vb = bid; vb < 12288; vb += nb) {
    if (vb < 4096) {
      // ---- maskbits: word[(bh*16+kt)*1024 + q], bit j = mask[bh,q,kt*64+j]!=0
      const int wi = vb * 256 + threadIdx.x;
      u64 b = 0;
      if (fmt == 0) {
        const uint4* mp = (const uint4*)mask + (size_t)wi * 4;
#pragma unroll
        for (int i = 0; i < 4; ++i) {
          uint4 v = mp[i];
          unsigned xw[4] = {v.x, v.y, v.z, v.w};
#pragma unroll
          for (int d = 0; d < 4; ++d)
#pragma unroll
            for (int by = 0; by < 4; ++by)
              if (xw[d] & (0xFFu << (by * 8))) b |= 1ULL << (i * 16 + d * 4 + by);
        }
      } else if (fmt != 3) {
        const uint4* mp = (const uint4*)mask + (size_t)wi * 16;
#pragma unroll
        for (int i = 0; i < 16; ++i) {
          uint4 v = mp[i];
          if (v.x) b |= 1ULL << (i * 4 + 0);
          if (v.y) b |= 1ULL << (i * 4 + 1);
          if (v.z) b |= 1ULL << (i * 4 + 2);
          if (v.w) b |= 1ULL << (i * 4 + 3);
        }
      } else {
        const uint4* mp = (const uint4*)mask + (size_t)wi * 32;
#pragma unroll
        for (int i = 0; i < 32; ++i) {
          uint4 v = mp[i];
          if (v.x | v.y) b |= 1ULL << (i * 2 + 0);
          if (v.z | v.w) b |= 1ULL << (i * 2 + 1);
        }
      }
      int bh = wi >> 14, q = (wi >> 4) & 1023, kt = wi & 15;
      bits[((size_t)bh * 16 + kt) * 1024 + q] = b;
    } else if (vb < 8192) {
      // ---- x f32 -> bf16
      int i = ((vb - 4096) * 256 + threadIdx.x) * 4;
      float4v v = *(const float4v*)(x + i);
      u16x4 o;
      o[0] = f2bf(v[0]); o[1] = f2bf(v[1]); o[2] = f2bf(v[2]); o[3] = f2bf(v[3]);
      *(u16x4*)(xb + i) = o;
    } else {
      // ---- W f32 [K][N] -> bf16 [N][K]
      int i = vb - 8192;
      int z = i >> 10, rest = i & 1023;
      const float* W = (z == 0) ? W0 : (z == 1) ? W1 : (z == 2) ? W2 : W3;
      u16* outw = Wt + (size_t)z * 1048576;
      int n0 = (rest & 31) * 32, k0 = (rest >> 5) * 32;
      int tx = threadIdx.x & 31, ty = threadIdx.x >> 5;
      __syncthreads();  // protect smem reuse across strided iterations
#pragma unroll
      for (int j = 0; j < 4; ++j)
        t[ty + 8 * j][tx] = W[(size_t)(k0 + ty + 8 * j) * 1024 + n0 + tx];
      __syncthreads();
#pragma unroll
      for (int j = 0; j < 4; ++j)
        outw[(size_t)(n0 + ty + 8 * j) * 1024 + k0 + tx] = f2bf(t[tx][ty + 8 * j]);
    }
  }
}

// ================= phase: QKV GEMM, 128x128 tile, C^T epilogue ===============
__device__ void phase_qkv(char* sm, const u16* __restrict__ A, const u16* __restrict__ Wt,
                          const float* __restrict__ b0, const float* __restrict__ b1,
                          const float* __restrict__ b2, const float* __restrict__ temp,
                          u16* __restrict__ qb, u16* __restrict__ kb, u16* __restrict__ vT,
                          int job) {
  u16* As = (u16*)sm;            // 128x32 bf16 = 8KB
  u16* Bs = (u16*)(sm + 8192);   // 128x32 bf16 = 8KB
  const int z = job >> 8, rest = job & 255;
  const int m0 = (rest >> 3) * 128, n0 = (rest & 7) * 128;
  const u16* Bt = Wt + (size_t)z * 1048576;
  const float* bias = (z == 0) ? b0 : (z == 1) ? b1 : b2;
  const int tid = threadIdx.x, lane = tid & 63, w = tid >> 6;
  const int l15 = lane & 15, l4 = lane >> 4;
  const int wr = w >> 1, wc = w & 1;

  f32x4 acc[4][4] = {};

  const int c0 = tid, c1 = 256 + tid;
  const u16* ga0 = A + (size_t)(m0 + (c0 >> 2)) * 1024 + (c0 & 3) * 8;
  const u16* ga1 = A + (size_t)(m0 + (c1 >> 2)) * 1024 + (c1 & 3) * 8;
  const u16* gb0 = Bt + (size_t)(n0 + (c0 >> 2)) * 1024 + (c0 & 3) * 8;
  const u16* gb1 = Bt + (size_t)(n0 + (c1 >> 2)) * 1024 + (c1 & 3) * 8;

  for (int kt = 0; kt < 1024; kt += 32) {
    gload16(ga0 + kt, As + c0 * 8);
    gload16(ga1 + kt, As + c1 * 8);
    gload16(gb0 + kt, Bs + c0 * 8);
    gload16(gb1 + kt, Bs + c1 * 8);
    __syncthreads();
    short8 af[4], bfr[4];
#pragma unroll
    for (int r = 0; r < 4; ++r)
      af[r] = *(const short8*)(As + (wr * 64 + r * 16 + l15) * 32 + l4 * 8);
#pragma unroll
    for (int c = 0; c < 4; ++c)
      bfr[c] = *(const short8*)(Bs + (wc * 64 + c * 16 + l15) * 32 + l4 * 8);
#pragma unroll
    for (int r = 0; r < 4; ++r)
#pragma unroll
      for (int c = 0; c < 4; ++c)
        acc[r][c] = __builtin_amdgcn_mfma_f32_16x16x32_bf16(bfr[c], af[r], acc[r][c], 0, 0, 0);
    __syncthreads();
  }

  float bvj[4][4];
#pragma unroll
  for (int c = 0; c < 4; ++c)
#pragma unroll
    for (int j = 0; j < 4; ++j)
      bvj[c][j] = bias[n0 + wc * 64 + c * 16 + l4 * 4 + j];
  const float fac = (z == 0) ? temp[(n0 + wc * 64) >> 6] * 0.18033688011112042f : 1.0f;

#pragma unroll
  for (int r = 0; r < 4; ++r) {
    const int mm = m0 + wr * 64 + r * 16 + l15;   // b*1024+s (lane-contiguous)
    const int b = mm >> 10, s = mm & 1023;
#pragma unroll
    for (int c = 0; c < 4; ++c) {
      const int n = n0 + wc * 64 + c * 16 + l4 * 4;
      if (z == 2) {
#pragma unroll
        for (int j = 0; j < 4; ++j)
          vT[((size_t)b * 1024 + n + j) * 1024 + s] = f2bf(acc[r][c][j] + bvj[c][j]);
      } else {
        unsigned lo = cvtpk((acc[r][c][0] + bvj[c][0]) * fac, (acc[r][c][1] + bvj[c][1]) * fac);
        unsigned hi = cvtpk((acc[r][c][2] + bvj[c][2]) * fac, (acc[r][c][3] + bvj[c][3]) * fac);
        unsigned o2[2] = {lo, hi};
        int hh = n >> 6, d = n & 63;
        u16* dst = (z == 0) ? qb : kb;
        *(unsigned long long*)(dst + ((((size_t)b * 16 + hh) * 1024 + s) * 64 + d)) =
            *(unsigned long long*)o2;
      }
    }
  }
}

// ================= phase: flash attention, 4 waves x 16q, P in-register ======
__device__ void phase_attn(char* sm, const u16* __restrict__ qb, const u16* __restrict__ kb,
                           const u16* __restrict__ vT, const u64* __restrict__ mbits,
                           u16* __restrict__ oh, int job) {
  u16* Ks = (u16*)sm;             // [2][64*64] = 16KB
  u16* Vs = (u16*)(sm + 16384);   // [2][64*64] = 16KB
  const int tid = threadIdx.x, lane = tid & 63, w = tid >> 6;
  const int l15 = lane & 15, l4 = lane >> 4;
  const int xcd = job & 7, rest = job >> 3;
  const int bh = xcd * 8 + (rest & 7), qx = rest >> 3;   // 8 xcd x 8 bh x 16 qx
  const int b = bh >> 4, h = bh & 15;
  const int q0 = qx * 64 + w * 16;
  const u16* qp = qb + ((size_t)bh * 1024 + q0) * 64;
  const u16* kp = kb + (size_t)bh * 1024 * 64;
  const u16* vp = vT + (size_t)bh * 64 * 1024;

  const int L0 = tid, L1 = tid + 256;
  const int r0 = L0 >> 3, c0 = ((L0 & 7) ^ (r0 & 7)) * 8;
  const int r1 = L1 >> 3, c1 = ((L1 & 7) ^ (r1 & 7)) * 8;
  const int swz8 = (l15 & 7) << 3;   // u16-index XOR for K reads
  const int vswz = l15 & 7;          // granule XOR for V reads

  short8 qf0 = *(const short8*)(qp + (size_t)l15 * 64 + l4 * 8);
  short8 qf1 = *(const short8*)(qp + (size_t)l15 * 64 + 32 + l4 * 8);

  float m = -1e30f, l = 0.f;
  f32x4 oacc[4] = {};   // O^T: d = db*16 + l4*4 + j, q = l15

  const u64* mb = mbits + (size_t)bh * 16 * 1024 + q0 + l15;
  u64 wcur = mb[0];

  gload16(kp + (size_t)r0 * 64 + c0, Ks + L0 * 8);
  gload16(kp + (size_t)r1 * 64 + c1, Ks + L1 * 8);
  gload16(vp + (size_t)r0 * 1024 + c0, Vs + L0 * 8);
  gload16(vp + (size_t)r1 * 1024 + c1, Vs + L1 * 8);

  for (int t = 0; t < 16; ++t) {
    const int base = (t & 1) * 4096;
    const int nbase = 4096 - base;
    __syncthreads();  // stage(t) drained (vmcnt(0) before barrier)

    if (t < 15) {
      const int k1 = (t + 1) * 64;
      gload16(kp + (size_t)(k1 + r0) * 64 + c0, Ks + nbase + L0 * 8);
      gload16(kp + (size_t)(k1 + r1) * 64 + c1, Ks + nbase + L1 * 8);
      gload16(vp + (size_t)r0 * 1024 + k1 + c0, Vs + nbase + L0 * 8);
      gload16(vp + (size_t)r1 * 1024 + k1 + c1, Vs + nbase + L1 * 8);
    }
    u64 wnext = (t < 15) ? mb[(t + 1) * 1024] : 0ULL;

    // ---- S^T = K Q^T ----
    f32x4 s[4] = {};
    __builtin_amdgcn_s_setprio(1);
#pragma unroll
    for (int cb = 0; cb < 4; ++cb) {
      const u16* kr = Ks + base + (cb * 16 + l15) * 64;
      short8 kf0 = *(const short8*)(kr + ((l4 * 8) ^ swz8));
      short8 kf1 = *(const short8*)(kr + ((32 + l4 * 8) ^ swz8));
      s[cb] = __builtin_amdgcn_mfma_f32_16x16x32_bf16(kf0, qf0, s[cb], 0, 0, 0);
      s[cb] = __builtin_amdgcn_mfma_f32_16x16x32_bf16(kf1, qf1, s[cb], 0, 0, 0);
    }
    __builtin_amdgcn_s_setprio(0);

    // ---- online softmax: raw-score max, mask applied post-exp ----
    float mt = fmaxf(fmaxf(s[0][0], s[0][1]), fmaxf(s[0][2], s[0][3]));
#pragma unroll
    for (int cb = 1; cb < 4; ++cb)
      mt = fmaxf(mt, fmaxf(fmaxf(s[cb][0], s[cb][1]), fmaxf(s[cb][2], s[cb][3])));
    mt = fmaxf(mt, __shfl_xor(mt, 16));
    mt = fmaxf(mt, __shfl_xor(mt, 32));
    if (!__all(mt <= m + 8.f)) {   // T13 defer-max
      float mnew = fmaxf(m, mt);
      float al = exp2f(m - mnew);
      l *= al;
#pragma unroll
      for (int db = 0; db < 4; ++db) oacc[db] *= al;
      m = mnew;
    }
    unsigned hws[4] = {(unsigned)wcur, (unsigned)(wcur >> 16),
                       (unsigned)(wcur >> 32), (unsigned)(wcur >> 48)};
    float rs = 0.f;
#pragma unroll
    for (int cb = 0; cb < 4; ++cb) {
#pragma unroll
      for (int j = 0; j < 4; ++j) {
        float p = exp2f(s[cb][j] - m);
        p = ((hws[cb] >> (l4 * 4 + j)) & 1) ? p : 0.f;
        rs += p;
        s[cb][j] = p;
      }
    }
    rs += __shfl_xor(rs, 16);
    rs += __shfl_xor(rs, 32);
    l += rs;

    // ---- P -> bf16 in-register (these ARE the PV B-fragments) ----
    PackSS pb0, pb1;
    pb0.u[0] = cvtpk(s[0][0], s[0][1]); pb0.u[1] = cvtpk(s[0][2], s[0][3]);
    pb0.u[2] = cvtpk(s[1][0], s[1][1]); pb0.u[3] = cvtpk(s[1][2], s[1][3]);
    pb1.u[0] = cvtpk(s[2][0], s[2][1]); pb1.u[1] = cvtpk(s[2][2], s[2][3]);
    pb1.u[2] = cvtpk(s[3][0], s[3][1]); pb1.u[3] = cvtpk(s[3][2], s[3][3]);

    // ---- O^T += V^T P^T (k-slot-permuted mfma; V via 2x b64 LDS reads) ----
    __builtin_amdgcn_s_setprio(1);
#pragma unroll
    for (int kg = 0; kg < 2; ++kg) {
#pragma unroll
      for (int db = 0; db < 4; ++db) {
        const u16* vrow = Vs + base + (db * 16 + l15) * 64;
        const int e0 = (((4 * kg + (l4 >> 1)) ^ vswz) << 3) + (l4 & 1) * 4;
        const int e1 = (((4 * kg + 2 + (l4 >> 1)) ^ vswz) << 3) + (l4 & 1) * 4;
        uint2v v0 = *(const uint2v*)(vrow + e0);
        uint2v v1 = *(const uint2v*)(vrow + e1);
        PackSS vf;
        vf.u[0] = v0[0]; vf.u[1] = v0[1]; vf.u[2] = v1[0]; vf.u[3] = v1[1];
        oacc[db] = __builtin_amdgcn_mfma_f32_16x16x32_bf16(
            vf.s, kg ? pb1.s : pb0.s, oacc[db], 0, 0, 0);
      }
    }
    __builtin_amdgcn_s_setprio(0);
    wcur = wnext;
  }

  float rl = 1.f / l;
  u16* orow = oh + ((size_t)b * 1024 + q0 + l15) * 1024 + h * 64;
#pragma unroll
  for (int db = 0; db < 4; ++db) {
    unsigned a0 = cvtpk(oacc[db][0] * rl, oacc[db][1] * rl);
    unsigned a1 = cvtpk(oacc[db][2] * rl, oacc[db][3] * rl);
    unsigned oA[2] = {a0, a1};
    *(unsigned long long*)(orow + db * 16 + l4 * 4) = *(unsigned long long*)oA;
  }
}

// ================= phase: O-proj GEMM, 64x64 tile, f32 C^T epilogue ==========
__device__ void phase_oproj(char* sm, const u16* __restrict__ A, const u16* __restrict__ Bt,
                            const float* __restrict__ bias, float* __restrict__ fo, int job) {
  u16* As = (u16*)sm;            // 64x32 = 4KB
  u16* Bs = (u16*)(sm + 4096);   // 64x32 = 4KB
  const int tid = threadIdx.x, lane = tid & 63, w = tid >> 6;
  const int l15 = lane & 15, l4 = lane >> 4;
  const int m0 = (job >> 4) * 64, n0 = (job & 15) * 64;
  const int wr = w >> 1, wc = w & 1;

  f32x4 acc[2][2] = {};

  const int rA = tid >> 2, cA = (tid & 3) * 8;
  const u16* ga = A + (size_t)(m0 + rA) * 1024 + cA;
  const u16* gb = Bt + (size_t)(n0 + rA) * 1024 + cA;

  for (int kt = 0; kt < 1024; kt += 32) {
    gload16(ga + kt, As + tid * 8);
    gload16(gb + kt, Bs + tid * 8);
    __syncthreads();
    short8 af[2], bfr[2];
#pragma unroll
    for (int r = 0; r < 2; ++r)
      af[r] = *(const short8*)(As + (wr * 32 + r * 16 + l15) * 32 + l4 * 8);
#pragma unroll
    for (int c = 0; c < 2; ++c)
      bfr[c] = *(const short8*)(Bs + (wc * 32 + c * 16 + l15) * 32 + l4 * 8);
#pragma unroll
    for (int r = 0; r < 2; ++r)
#pragma unroll
      for (int c = 0; c < 2; ++c)
        acc[r][c] = __builtin_amdgcn_mfma_f32_16x16x32_bf16(bfr[c], af[r], acc[r][c], 0, 0, 0);
    __syncthreads();
  }

  float bvj[2][4];
#pragma unroll
  for (int c = 0; c < 2; ++c)
#pragma unroll
    for (int j = 0; j < 4; ++j)
      bvj[c][j] = bias[n0 + wc * 32 + c * 16 + l4 * 4 + j];

#pragma unroll
  for (int r = 0; r < 2; ++r) {
    const int mm = m0 + wr * 32 + r * 16 + l15;
#pragma unroll
    for (int c = 0; c < 2; ++c) {
      const int n = n0 + wc * 32 + c * 16 + l4 * 4;
      float4v o;
#pragma unroll
      for (int j = 0; j < 4; ++j) o[j] = acc[r][c][j] + bvj[c][j];
      *(float4v*)(fo + (size_t)mm * 1024 + n) = o;
    }
  }
}

// ================= fused cooperative kernel ==================================
__global__ __launch_bounds__(256, 4)
void fused_kernel(const void* mask, u64* mbits, const float* x, u16* xb,
                  const float* Wq, const float* Wk, const float* Wv, const float* Wo,
                  u16* Wt, const float* bq, const float* bk, const float* bv,
                  const float* bo, const float* temp,
                  u16* qb, u16* kb, u16* vT, u16* oh, float* out) {
  __shared__ __align__(16) char sm[32768];
  cg::grid_group grid = cg::this_grid();
  phase_prep(sm, mask, mbits, x, xb, Wq, Wk, Wv, Wo, Wt, blockIdx.x, gridDim.x);
  grid.sync();
  if (blockIdx.x < 768)
    phase_qkv(sm, xb, Wt, bq, bk, bv, temp, qb, kb, vT, blockIdx.x);
  grid.sync();
  phase_attn(sm, qb, kb, vT, mbits, oh, blockIdx.x);
  grid.sync();
  phase_oproj(sm, oh, Wt + (size_t)3 * 1048576, bo, out, blockIdx.x);
}

// ================= fallback (non-cooperative) kernels ========================
__global__ __launch_bounds__(256, 4)
void k_prep(const void* mask, u64* mbits, const float* x, u16* xb,
            const float* Wq, const float* Wk, const float* Wv, const float* Wo, u16* Wt) {
  __shared__ __align__(16) char sm[32768];
  phase_prep(sm, mask, mbits, x, xb, Wq, Wk, Wv, Wo, Wt, blockIdx.x, gridDim.x);
}
__global__ __launch_bounds__(256, 4)
void k_qkv(const u16* xb, const u16* Wt, const float* bq, const float* bk,
           const float* bv, const float* temp, u16* qb, u16* kb, u16* vT) {
  __shared__ __align__(16) char sm[32768];
  phase_qkv(sm, xb, Wt, bq, bk, bv, temp, qb, kb, vT, blockIdx.x);
}
__global__ __launch_bounds__(256, 4)
void k_attn(const u16* qb, const u16* kb, const u16* vT, const u64* mbits, u16* oh) {
  __shared__ __align__(16) char sm[32768];
  phase_attn(sm, qb, kb, vT, mbits, oh, blockIdx.x);
}
__global__ __launch_bounds__(256, 4)
void k_oproj(const u16* oh, const u16* WtO, const float* bo, float* out) {
  __shared__ __align__(16) char sm[32768];
  phase_oproj(sm, oh, WtO, bo, out, blockIdx.x);
}

// ================= launch ====================================================
extern "C" void kernel_launch(void* const* d_in, const int* in_sizes, int n_in,
                              void* d_out, int out_size, void* d_ws, size_t ws_size,
                              hipStream_t stream) {
  const float* x = (const float*)d_in[0];
  const float* Wq = (const float*)d_in[1];
  const float* bq = (const float*)d_in[2];
  const float* Wk = (const float*)d_in[3];
  const float* bk = (const float*)d_in[4];
  const float* Wv = (const float*)d_in[5];
  const float* bv = (const float*)d_in[6];
  const float* Wo = (const float*)d_in[7];
  const float* bo = (const float*)d_in[8];
  const float* temp = (const float*)d_in[9];
  const void* mask = (const void*)d_in[10];

  char* ws = (char*)d_ws;
  u16* xb = (u16*)(ws + 256);                 // 8 MiB (x bf16; aliased as oh later)
  u16* Wt = xb + (size_t)4 * 1024 * 1024;     // 8 MiB (4x weight^T bf16)
  u16* qbuf = Wt + (size_t)4 * 1024 * 1024;   // 8 MiB [B,H,S,D] (q pre-scaled)
  u16* kbuf = qbuf + (size_t)4 * 1024 * 1024; // 8 MiB [B,H,S,D]
  u16* vTb = kbuf + (size_t)4 * 1024 * 1024;  // 8 MiB [B,H,D,S]
  u64* mbits = (u64*)(vTb + (size_t)4 * 1024 * 1024);  // 8 MiB bitmask
  u16* oh = xb;                               // alias: xb dead after QKV GEMM
  float* outp = (float*)d_out;

  void* ka[] = {(void*)&mask, (void*)&mbits, (void*)&x, (void*)&xb,
                (void*)&Wq, (void*)&Wk, (void*)&Wv, (void*)&Wo, (void*)&Wt,
                (void*)&bq, (void*)&bk, (void*)&bv, (void*)&bo, (void*)&temp,
                (void*)&qbuf, (void*)&kbuf, (void*)&vTb, (void*)&oh, (void*)&outp};
  hipError_t e = hipLaunchCooperativeKernel((const void*)fused_kernel,
                                            dim3(1024), dim3(256), ka, 0, stream);
  if (e != hipSuccess) {
    (void)hipGetLastError();  // clear sticky error; fall back to 4 dispatches
    k_prep<<<1024, 256, 0, stream>>>(mask, mbits, x, xb, Wq, Wk, Wv, Wo, Wt);
    k_qkv<<<768, 256, 0, stream>>>(xb, Wt, bq, bk, bv, temp, qbuf, kbuf, vTb);
    k_attn<<<1024, 256, 0, stream>>>(qbuf, kbuf, vTb, mbits, oh);
    k_oproj<<<1024, 256, 0, stream>>>(oh, Wt + (size_t)3 * 1048576, bo, outp);
  }
}

// Round 10
// 195.697 us; speedup vs baseline: 3.3139x; 3.3139x over previous
//
#include <hip/hip_runtime.h>

typedef unsigned short u16;
typedef short short8 __attribute__((ext_vector_type(8)));
typedef float f32x4 __attribute__((ext_vector_type(4)));
typedef float float4v __attribute__((ext_vector_type(4)));
typedef u16 u16x4 __attribute__((ext_vector_type(4)));
typedef unsigned uint2v __attribute__((ext_vector_type(2)));
typedef unsigned long long u64;

// ---------- helpers ----------
__device__ __forceinline__ u16 f2bf(float f) {
  union { float f; unsigned u; } v; v.f = f;
  unsigned r = v.u + 0x7FFFu + ((v.u >> 16) & 1u);   // round-to-nearest-even
  return (u16)(r >> 16);
}

__device__ __forceinline__ unsigned cvtpk(float lo, float hi) {
  unsigned r;
  asm("v_cvt_pk_bf16_f32 %0, %1, %2" : "=v"(r) : "v"(lo), "v"(hi));
  return r;
}

__device__ __forceinline__ void gload16(const u16* g, u16* l) {
  __builtin_amdgcn_global_load_lds(
      (const __attribute__((address_space(1))) void*)g,
      (__attribute__((address_space(3))) void*)l, 16, 0, 0);
}

union PackSS { unsigned u[4]; short8 s; };

// ========== prep: maskbits (0..4095), xcvt (4096..8191), wcvt (8192..12287) ==
// maskbits: thread's OUTPUT word = global linear id (coalesced 8B writes);
// source reads are 64B-line-granular strided (HBM-efficient).
__global__ __launch_bounds__(256)
void prep_kernel(const void* __restrict__ mask, u64* __restrict__ bits,
                 const float* __restrict__ x, u16* __restrict__ xb,
                 const float* __restrict__ W0, const float* __restrict__ W1,
                 const float* __restrict__ W2, const float* __restrict__ W3,
                 u16* __restrict__ Wt) {
  __shared__ float t[32][33];
  __shared__ int sf;
  const int bid = blockIdx.x;
  if (bid < 4096) {
    // ---- detect mask dtype from first 4KB (fmt: 0=u8, 1=i32, 2=f32, 3=i64) ----
    if (threadIdx.x == 0) sf = 0;
    __syncthreads();
    {
      uint4 v = ((const uint4*)mask)[threadIdx.x];
      unsigned xs[4] = {v.x, v.y, v.z, v.w};
      int f = 0;
#pragma unroll
      for (int d = 0; d < 4; ++d) {
        unsigned u = xs[d];
        if (u == 0x3F800000u) f |= 1;
        if (u & 0xFFFFFF00u) f |= 2;
        if ((d & 1) && u) f |= 4;
      }
      if (f) atomicOr(&sf, f);
    }
    __syncthreads();
    const int fl = sf;
    const int fmt = (fl & 1) ? 2 : ((fl & 2) ? 0 : ((fl & 4) ? 1 : 3));

    // word index = linear; decode (bh, kt, q); layout bits[(bh*16+kt)*1024+q]
    const int wi = bid * 256 + threadIdx.x;
    const int bh = wi >> 14, kt = (wi >> 10) & 15, q = wi & 1023;
    u64 b = 0;
    if (fmt == 0) {
      const uint4* mp = (const uint4*)mask + (((size_t)bh << 16) + (q << 6) + (kt << 2));
#pragma unroll
      for (int i = 0; i < 4; ++i) {
        uint4 v = mp[i];
        unsigned xw[4] = {v.x, v.y, v.z, v.w};
#pragma unroll
        for (int d = 0; d < 4; ++d)
#pragma unroll
          for (int by = 0; by < 4; ++by)
            if (xw[d] & (0xFFu << (by * 8))) b |= 1ULL << (i * 16 + d * 4 + by);
      }
    } else if (fmt != 3) {  // 4-byte elements (i32 / f32)
      const uint4* mp = (const uint4*)mask + (((size_t)bh << 18) + (q << 8) + (kt << 4));
#pragma unroll
      for (int i = 0; i < 16; ++i) {
        uint4 v = mp[i];
        if (v.x) b |= 1ULL << (i * 4 + 0);
        if (v.y) b |= 1ULL << (i * 4 + 1);
        if (v.z) b |= 1ULL << (i * 4 + 2);
        if (v.w) b |= 1ULL << (i * 4 + 3);
      }
    } else {  // i64
      const uint4* mp = (const uint4*)mask + (((size_t)bh << 19) + (q << 9) + (kt << 5));
#pragma unroll
      for (int i = 0; i < 32; ++i) {
        uint4 v = mp[i];
        if (v.x | v.y) b |= 1ULL << (i * 2 + 0);
        if (v.z | v.w) b |= 1ULL << (i * 2 + 1);
      }
    }
    bits[wi] = b;
  } else if (bid < 8192) {
    // ---- x f32 -> bf16 ----
    int i = ((bid - 4096) * 256 + threadIdx.x) * 4;
    float4v v = *(const float4v*)(x + i);
    u16x4 o;
    o[0] = f2bf(v[0]); o[1] = f2bf(v[1]); o[2] = f2bf(v[2]); o[3] = f2bf(v[3]);
    *(u16x4*)(xb + i) = o;
  } else {
    // ---- W f32 [K][N] -> bf16 [N][K] ----
    int i = bid - 8192;
    int z = i >> 10, rest = i & 1023;
    const float* W = (z == 0) ? W0 : (z == 1) ? W1 : (z == 2) ? W2 : W3;
    u16* outw = Wt + (size_t)z * 1048576;
    int n0 = (rest & 31) * 32, k0 = (rest >> 5) * 32;
    int tx = threadIdx.x & 31, ty = threadIdx.x >> 5;
#pragma unroll
    for (int j = 0; j < 4; ++j)
      t[ty + 8 * j][tx] = W[(size_t)(k0 + ty + 8 * j) * 1024 + n0 + tx];
    __syncthreads();
#pragma unroll
    for (int j = 0; j < 4; ++j)
      outw[(size_t)(n0 + ty + 8 * j) * 1024 + k0 + tx] = f2bf(t[tx][ty + 8 * j]);
  }
}

// ========== QKV GEMM: 128x128 tile, BK=64, swizzled LDS, C^T epilogue ========
__global__ __launch_bounds__(256)
void qkv_kernel(const u16* __restrict__ A, const u16* __restrict__ Wt,
                const float* __restrict__ b0, const float* __restrict__ b1,
                const float* __restrict__ b2, const float* __restrict__ temp,
                u16* __restrict__ qb, u16* __restrict__ kb, u16* __restrict__ vT) {
  __shared__ u16 As[128 * 64];   // 16 KiB
  __shared__ u16 Bs[128 * 64];   // 16 KiB
  const int tid = threadIdx.x, lane = tid & 63, w = tid >> 6;
  const int l15 = lane & 15, l4 = lane >> 4;
  const int m0 = blockIdx.x * 128, n0 = blockIdx.y * 128;
  const int z = blockIdx.z;
  const u16* Bt = Wt + (size_t)z * 1048576;
  const float* bias = (z == 0) ? b0 : (z == 1) ? b1 : b2;
  const int wr = w >> 1, wc = w & 1;

  f32x4 acc[4][4] = {};

  // staging: 4 chunks each (A,B); chunk c: row=c>>3, src granule=(c&7)^(row&7)
  int arow[4], acg[4];
#pragma unroll
  for (int i = 0; i < 4; ++i) {
    int c = tid + 256 * i;
    arow[i] = c >> 3; acg[i] = ((c & 7) ^ (arow[i] & 7)) * 8;
  }

  for (int kt = 0; kt < 1024; kt += 64) {
#pragma unroll
    for (int i = 0; i < 4; ++i) {
      gload16(A + (size_t)(m0 + arow[i]) * 1024 + kt + acg[i], As + (tid + 256 * i) * 8);
      gload16(Bt + (size_t)(n0 + arow[i]) * 1024 + kt + acg[i], Bs + (tid + 256 * i) * 8);
    }
    __syncthreads();
#pragma unroll
    for (int kk = 0; kk < 2; ++kk) {
      short8 af[4], bf[4];
#pragma unroll
      for (int r = 0; r < 4; ++r) {
        int row = wr * 64 + r * 16 + l15;
        af[r] = *(const short8*)(As + row * 64 + (((kk * 4 + l4) ^ (row & 7)) * 8));
      }
#pragma unroll
      for (int c = 0; c < 4; ++c) {
        int row = wc * 64 + c * 16 + l15;
        bf[c] = *(const short8*)(Bs + row * 64 + (((kk * 4 + l4) ^ (row & 7)) * 8));
      }
#pragma unroll
      for (int r = 0; r < 4; ++r)
#pragma unroll
        for (int c = 0; c < 4; ++c)
          acc[r][c] = __builtin_amdgcn_mfma_f32_16x16x32_bf16(bf[c], af[r], acc[r][c], 0, 0, 0);
    }
    __syncthreads();
  }

  // C^T epilogue: acc row = n-part (c*16 + l4*4 + j), col = m-part (r*16 + l15)
  float bvj[4][4];
#pragma unroll
  for (int c = 0; c < 4; ++c)
#pragma unroll
    for (int j = 0; j < 4; ++j)
      bvj[c][j] = bias[n0 + wc * 64 + c * 16 + l4 * 4 + j];
  const float fac = (z == 0) ? temp[(n0 + wc * 64) >> 6] * 0.18033688011112042f : 1.0f;

#pragma unroll
  for (int r = 0; r < 4; ++r) {
    const int mm = m0 + wr * 64 + r * 16 + l15;   // b*1024+s (lane-contiguous)
    const int b = mm >> 10, s = mm & 1023;
#pragma unroll
    for (int c = 0; c < 4; ++c) {
      const int n = n0 + wc * 64 + c * 16 + l4 * 4;
      if (z == 2) {
#pragma unroll
        for (int j = 0; j < 4; ++j)
          vT[((size_t)b * 1024 + n + j) * 1024 + s] = f2bf(acc[r][c][j] + bvj[c][j]);
      } else {
        unsigned lo = cvtpk((acc[r][c][0] + bvj[c][0]) * fac, (acc[r][c][1] + bvj[c][1]) * fac);
        unsigned hi = cvtpk((acc[r][c][2] + bvj[c][2]) * fac, (acc[r][c][3] + bvj[c][3]) * fac);
        unsigned o2[2] = {lo, hi};
        int hh = n >> 6, d = n & 63;
        u16* dst = (z == 0) ? qb : kb;
        *(unsigned long long*)(dst + ((((size_t)b * 16 + hh) * 1024 + s) * 64 + d)) =
            *(unsigned long long*)o2;
      }
    }
  }
}

// ========== flash attention: 4 waves x 16q, KBLK=64, P in-register ===========
__global__ __launch_bounds__(256, 4)
void attn_kernel(const u16* __restrict__ qb, const u16* __restrict__ kb,
                 const u16* __restrict__ vT, const u64* __restrict__ mbits,
                 u16* __restrict__ oh) {
  __shared__ u16 Ks[2][64 * 64];   // 16 KiB
  __shared__ u16 Vs[2][64 * 64];   // 16 KiB
  const int tid = threadIdx.x, lane = tid & 63, w = tid >> 6;
  const int l15 = lane & 15, l4 = lane >> 4;
  const int id = blockIdx.x;           // 1024: xcd(8) x bh-sub(8) x qx(16)
  const int xcd = id & 7, rest = id >> 3;
  const int bh = xcd * 8 + (rest & 7), qx = rest >> 3;
  const int b = bh >> 4, h = bh & 15;
  const int q0 = qx * 64 + w * 16;
  const u16* qp = qb + ((size_t)bh * 1024 + q0) * 64;
  const u16* kp = kb + (size_t)bh * 1024 * 64;
  const u16* vp = vT + (size_t)bh * 64 * 1024;

  const int L0 = tid, L1 = tid + 256;
  const int r0 = L0 >> 3, c0 = ((L0 & 7) ^ (r0 & 7)) * 8;
  const int r1 = L1 >> 3, c1 = ((L1 & 7) ^ (r1 & 7)) * 8;
  const int swz8 = (l15 & 7) << 3;   // u16-index XOR for K reads
  const int vswz = l15 & 7;          // granule XOR for V reads

  short8 qf0 = *(const short8*)(qp + (size_t)l15 * 64 + l4 * 8);
  short8 qf1 = *(const short8*)(qp + (size_t)l15 * 64 + 32 + l4 * 8);

  float m = -1e30f, l = 0.f;
  f32x4 oacc[4] = {};   // O^T: d = db*16 + l4*4 + j, q = l15

  const u64* mb = mbits + (size_t)bh * 16 * 1024 + q0 + l15;
  u64 wcur = mb[0];

  gload16(kp + (size_t)r0 * 64 + c0, &Ks[0][L0 * 8]);
  gload16(kp + (size_t)r1 * 64 + c1, &Ks[0][L1 * 8]);
  gload16(vp + (size_t)r0 * 1024 + c0, &Vs[0][L0 * 8]);
  gload16(vp + (size_t)r1 * 1024 + c1, &Vs[0][L1 * 8]);

  for (int t = 0; t < 16; ++t) {
    const int buf = t & 1;
    __syncthreads();  // stage(t) drained (vmcnt(0) before barrier)

    if (t < 15) {  // stage t+1 (hidden under compute of t)
      const int k1 = (t + 1) * 64;
      gload16(kp + (size_t)(k1 + r0) * 64 + c0, &Ks[buf ^ 1][L0 * 8]);
      gload16(kp + (size_t)(k1 + r1) * 64 + c1, &Ks[buf ^ 1][L1 * 8]);
      gload16(vp + (size_t)r0 * 1024 + k1 + c0, &Vs[buf ^ 1][L0 * 8]);
      gload16(vp + (size_t)r1 * 1024 + k1 + c1, &Vs[buf ^ 1][L1 * 8]);
    }
    u64 wnext = (t < 15) ? mb[(t + 1) * 1024] : 0ULL;

    // ---- S^T = K Q^T ----
    f32x4 s[4] = {};
    __builtin_amdgcn_s_setprio(1);
#pragma unroll
    for (int cb = 0; cb < 4; ++cb) {
      const u16* kr = &Ks[buf][(cb * 16 + l15) * 64];
      short8 kf0 = *(const short8*)(kr + ((l4 * 8) ^ swz8));
      short8 kf1 = *(const short8*)(kr + ((32 + l4 * 8) ^ swz8));
      s[cb] = __builtin_amdgcn_mfma_f32_16x16x32_bf16(kf0, qf0, s[cb], 0, 0, 0);
      s[cb] = __builtin_amdgcn_mfma_f32_16x16x32_bf16(kf1, qf1, s[cb], 0, 0, 0);
    }
    __builtin_amdgcn_s_setprio(0);

    // ---- online softmax: raw-score max, mask applied post-exp ----
    float mt = fmaxf(fmaxf(s[0][0], s[0][1]), fmaxf(s[0][2], s[0][3]));
#pragma unroll
    for (int cb = 1; cb < 4; ++cb)
      mt = fmaxf(mt, fmaxf(fmaxf(s[cb][0], s[cb][1]), fmaxf(s[cb][2], s[cb][3])));
    mt = fmaxf(mt, __shfl_xor(mt, 16));
    mt = fmaxf(mt, __shfl_xor(mt, 32));
    if (!__all(mt <= m + 8.f)) {   // T13 defer-max
      float mnew = fmaxf(m, mt);
      float al = exp2f(m - mnew);
      l *= al;
#pragma unroll
      for (int db = 0; db < 4; ++db) oacc[db] *= al;
      m = mnew;
    }
    unsigned hws[4] = {(unsigned)wcur, (unsigned)(wcur >> 16),
                       (unsigned)(wcur >> 32), (unsigned)(wcur >> 48)};
    float rs = 0.f;
#pragma unroll
    for (int cb = 0; cb < 4; ++cb) {
#pragma unroll
      for (int j = 0; j < 4; ++j) {
        float p = exp2f(s[cb][j] - m);
        p = ((hws[cb] >> (l4 * 4 + j)) & 1) ? p : 0.f;
        rs += p;
        s[cb][j] = p;
      }
    }
    rs += __shfl_xor(rs, 16);
    rs += __shfl_xor(rs, 32);
    l += rs;

    // ---- P -> bf16 in-register (these ARE the PV B-fragments) ----
    PackSS pb0, pb1;
    pb0.u[0] = cvtpk(s[0][0], s[0][1]); pb0.u[1] = cvtpk(s[0][2], s[0][3]);
    pb0.u[2] = cvtpk(s[1][0], s[1][1]); pb0.u[3] = cvtpk(s[1][2], s[1][3]);
    pb1.u[0] = cvtpk(s[2][0], s[2][1]); pb1.u[1] = cvtpk(s[2][2], s[2][3]);
    pb1.u[2] = cvtpk(s[3][0], s[3][1]); pb1.u[3] = cvtpk(s[3][2], s[3][3]);

    // ---- O^T += V^T P^T (k-slot-permuted mfma; V via 2x b64 LDS reads) ----
    __builtin_amdgcn_s_setprio(1);
#pragma unroll
    for (int kg = 0; kg < 2; ++kg) {
#pragma unroll
      for (int db = 0; db < 4; ++db) {
        const u16* vrow = &Vs[buf][(db * 16 + l15) * 64];
        const int e0 = (((4 * kg + (l4 >> 1)) ^ vswz) << 3) + (l4 & 1) * 4;
        const int e1 = (((4 * kg + 2 + (l4 >> 1)) ^ vswz) << 3) + (l4 & 1) * 4;
        uint2v v0 = *(const uint2v*)(vrow + e0);
        uint2v v1 = *(const uint2v*)(vrow + e1);
        PackSS vf;
        vf.u[0] = v0[0]; vf.u[1] = v0[1]; vf.u[2] = v1[0]; vf.u[3] = v1[1];
        oacc[db] = __builtin_amdgcn_mfma_f32_16x16x32_bf16(
            vf.s, kg ? pb1.s : pb0.s, oacc[db], 0, 0, 0);
      }
    }
    __builtin_amdgcn_s_setprio(0);
    wcur = wnext;
  }

  float rl = 1.f / l;
  u16* orow = oh + ((size_t)b * 1024 + q0 + l15) * 1024 + h * 64;
#pragma unroll
  for (int db = 0; db < 4; ++db) {
    unsigned a0 = cvtpk(oacc[db][0] * rl, oacc[db][1] * rl);
    unsigned a1 = cvtpk(oacc[db][2] * rl, oacc[db][3] * rl);
    unsigned oA[2] = {a0, a1};
    *(unsigned long long*)(orow + db * 16 + l4 * 4) = *(unsigned long long*)oA;
  }
}

// ========== O-proj GEMM: 128x64 tile, BK=64, swizzled LDS, f32 C^T ===========
__global__ __launch_bounds__(256)
void oproj_kernel(const u16* __restrict__ A, const u16* __restrict__ Bt,
                  const float* __restrict__ bias, float* __restrict__ fo) {
  __shared__ u16 As[128 * 64];   // 16 KiB
  __shared__ u16 Bs[64 * 64];    //  8 KiB
  const int tid = threadIdx.x, lane = tid & 63, w = tid >> 6;
  const int l15 = lane & 15, l4 = lane >> 4;
  const int m0 = blockIdx.x * 128, n0 = blockIdx.y * 64;
  const int wr = w >> 1, wc = w & 1;

  f32x4 acc[4][2] = {};

  int arow[4], acg[4];
#pragma unroll
  for (int i = 0; i < 4; ++i) {
    int c = tid + 256 * i;
    arow[i] = c >> 3; acg[i] = ((c & 7) ^ (arow[i] & 7)) * 8;
  }

  for (int kt = 0; kt < 1024; kt += 64) {
#pragma unroll
    for (int i = 0; i < 4; ++i)
      gload16(A + (size_t)(m0 + arow[i]) * 1024 + kt + acg[i], As + (tid + 256 * i) * 8);
#pragma unroll
    for (int i = 0; i < 2; ++i)
      gload16(Bt + (size_t)(n0 + arow[i]) * 1024 + kt + acg[i], Bs + (tid + 256 * i) * 8);
    __syncthreads();
#pragma unroll
    for (int kk = 0; kk < 2; ++kk) {
      short8 af[4], bf[2];
#pragma unroll
      for (int r = 0; r < 4; ++r) {
        int row = wr * 64 + r * 16 + l15;
        af[r] = *(const short8*)(As + row * 64 + (((kk * 4 + l4) ^ (row & 7)) * 8));
      }
#pragma unroll
      for (int c = 0; c < 2; ++c) {
        int row = wc * 32 + c * 16 + l15;
        bf[c] = *(const short8*)(Bs + row * 64 + (((kk * 4 + l4) ^ (row & 7)) * 8));
      }
#pragma unroll
      for (int r = 0; r < 4; ++r)
#pragma unroll
        for (int c = 0; c < 2; ++c)
          acc[r][c] = __builtin_amdgcn_mfma_f32_16x16x32_bf16(bf[c], af[r], acc[r][c], 0, 0, 0);
    }
    __syncthreads();
  }

  float bvj[2][4];
#pragma unroll
  for (int c = 0; c < 2; ++c)
#pragma unroll
    for (int j = 0; j < 4; ++j)
      bvj[c][j] = bias[n0 + wc * 32 + c * 16 + l4 * 4 + j];

#pragma unroll
  for (int r = 0; r < 4; ++r) {
    const int mm = m0 + wr * 64 + r * 16 + l15;
#pragma unroll
    for (int c = 0; c < 2; ++c) {
      const int n = n0 + wc * 32 + c * 16 + l4 * 4;
      float4v o;
#pragma unroll
      for (int j = 0; j < 4; ++j) o[j] = acc[r][c][j] + bvj[c][j];
      *(float4v*)(fo + (size_t)mm * 1024 + n) = o;
    }
  }
}

// ================= launch ====================================================
extern "C" void kernel_launch(void* const* d_in, const int* in_sizes, int n_in,
                              void* d_out, int out_size, void* d_ws, size_t ws_size,
                              hipStream_t stream) {
  const float* x = (const float*)d_in[0];
  const float* Wq = (const float*)d_in[1];
  const float* bq = (const float*)d_in[2];
  const float* Wk = (const float*)d_in[3];
  const float* bk = (const float*)d_in[4];
  const float* Wv = (const float*)d_in[5];
  const float* bv = (const float*)d_in[6];
  const float* Wo = (const float*)d_in[7];
  const float* bo = (const float*)d_in[8];
  const float* temp = (const float*)d_in[9];
  const void* mask = (const void*)d_in[10];

  char* ws = (char*)d_ws;
  u16* xb = (u16*)(ws + 256);                 // 8 MiB (x bf16; aliased as oh later)
  u16* Wt = xb + (size_t)4 * 1024 * 1024;     // 8 MiB (4x weight^T bf16)
  u16* qbuf = Wt + (size_t)4 * 1024 * 1024;   // 8 MiB [B,H,S,D] (q pre-scaled)
  u16* kbuf = qbuf + (size_t)4 * 1024 * 1024; // 8 MiB [B,H,S,D]
  u16* vTb = kbuf + (size_t)4 * 1024 * 1024;  // 8 MiB [B,H,D,S]
  u64* mbits = (u64*)(vTb + (size_t)4 * 1024 * 1024);  // 8 MiB bitmask
  u16* oh = xb;                               // alias: xb dead after QKV GEMM

  prep_kernel<<<12288, 256, 0, stream>>>(mask, mbits, x, xb, Wq, Wk, Wv, Wo, Wt);
  qkv_kernel<<<dim3(32, 8, 3), 256, 0, stream>>>(
      xb, Wt, bq, bk, bv, temp, qbuf, kbuf, vTb);
  attn_kernel<<<1024, 256, 0, stream>>>(qbuf, kbuf, vTb, mbits, oh);
  oproj_kernel<<<dim3(32, 16), 256, 0, stream>>>(
      oh, Wt + (size_t)3 * 1048576, bo, (float*)d_out);
}